// Round 6
// baseline (99.977 us; speedup 1.0000x reference)
//
#include <hip/hip_runtime.h>
#include <hip/hip_bf16.h>
#include <math.h>

// Chamfer distance via K-packed MFMA, B=8, N=M=8192, D=3, fp32.
//   C[m][n] = q_m.r_n - 0.5*||r_n||^2 via ONE v_mfma_f32_32x32x16_bf16:
//     lanes<32  (k0-7) : A={qh,1, ql,0}  B={rh,wh, rh,wh}
//     lanes>=32 (k8-15): A={qh,1, 0,0}   B={rl,wl, 0,0}
//   (hi/lo bf16 split; dropped ql.rl term ~2^-17 relative)
//   min_j d2 = ||q||^2_fp32 - 2*max_n C, clamped at 0.
// R12: nn pinned at ~42us across 4 structurally different bodies. R0 warm
// counters decode as: CU-iter period 787cy = MFMA 256 (32%) + VALU 360 (46%)
// + latency residue - the pipes SERIALIZE instead of overlapping, because
// (a) 2 waves/SIMD and (b) per-stage __syncthreads re-phased all waves into
// lockstep (everyone folds together, everyone MFMAs together), and R0's
// 1-iter prefetch (<L2 latency) added idle. Fix:
//   - recB is L2-resident (4MB) -> drop LDS staging entirely (mistake #7)
//   - global->register streaming, ping-pong 8-tile groups = 4-iter (~250cy+)
//     prefetch distance, all statically named (rule #20)
//   - ZERO barriers in the main loop (epilogue LDS is wave-private) ->
//     waves free-run and anti-phase; MFMA/VALU overlap cross-wave
//   - per-wave start rotated by quarter-chunk ((wave+bx)&3, &127 wrap):
//     de-convoys L2 access; max-fold is order-independent so rotation is
//     correctness-neutral; wrapped prefetch loads are valid-but-unused
//   - intrinsic MFMA (hazard recognizer active; R11 proved absmax 0.0)
// Predicted: nn 42 -> 17-24us, total ~73-80. Pre-commit: total ~98 again =>
// nn loop exonerated; R13 fuses kernels (dispatch overhead).

#define BLOCK 256
#define WAVES 4
#define QPW 64        // queries per wave (two 32-row MFMA groups)
#define NCHUNK 2      // ref-dim split across blockIdx.y

typedef short short8 __attribute__((ext_vector_type(8)));
typedef float f32x16 __attribute__((ext_vector_type(16)));

__device__ __forceinline__ unsigned int bf16hi(float f) {
    __hip_bfloat16 h = __float2bfloat16(f);
    return (unsigned int)*reinterpret_cast<unsigned short*>(&h);
}
__device__ __forceinline__ float bf16f(unsigned int u) {
    unsigned short us = (unsigned short)u;
    __hip_bfloat16 h;
    *reinterpret_cast<unsigned short*>(&h) = us;
    return __bfloat162float(h);
}

#define MFMA(a, b, c) __builtin_amdgcn_mfma_f32_32x32x16_bf16((a), (b), (c), 0, 0, 0)

union U4S { uint4 v; short8 s; };

// Per point:
//   recQ: one 16B record {xh|yh, zh|wh, xl|yl, zl|wl}, w = -0.5*||p||^2
//   recB: pre-expanded B-fragment stream, tile t = points [32t,32t+32),
//         1024B per tile:
//           bytes [t*1024 + m*16]       = {hx,hz, hx,hz}  (hi dup, lanes<32)
//           bytes [t*1024 + 512 + m*16] = {lx,lz, 0, 0}   (lo,     lanes>=32)
//   q2:   fp32 ||p||^2 (exact) for the reduce pass.
__global__ void prep_kernel(const float* __restrict__ gts, const float* __restrict__ preds,
                            int nG, int nP, uint4* __restrict__ recQ,
                            unsigned char* __restrict__ recB, float* __restrict__ q2,
                            float* out) {
    const int idx = blockIdx.x * blockDim.x + threadIdx.x;
    if (idx == 0) out[0] = 0.0f;
    if (idx >= nG + nP) return;
    const float* src;
    unsigned char* rb;
    if (idx < nG) {
        src = gts + 3 * (size_t)idx;
        rb  = recB + (size_t)(idx >> 5) * 1024 + (size_t)(idx & 31) * 16;
    } else {
        const int j = idx - nG;
        src = preds + 3 * (size_t)j;
        rb  = recB + (size_t)nG * 32 + (size_t)(j >> 5) * 1024 + (size_t)(j & 31) * 16;
    }
    const float x = src[0], y = src[1], z = src[2];
    const float n2 = x * x + y * y + z * z;
    const float w = -0.5f * n2;
    q2[idx] = n2;
    const unsigned int xh = bf16hi(x), yh = bf16hi(y), zh = bf16hi(z), wh = bf16hi(w);
    const unsigned int xl = bf16hi(x - bf16f(xh));
    const unsigned int yl = bf16hi(y - bf16f(yh));
    const unsigned int zl = bf16hi(z - bf16f(zh));
    const unsigned int wl = bf16hi(w - bf16f(wh));
    const unsigned int hx = xh | (yh << 16), hz = zh | (wh << 16);
    const unsigned int lx = xl | (yl << 16), lz = zl | (wl << 16);
    recQ[idx] = make_uint4(hx, hz, lx, lz);
    *(uint4*)(rb)       = make_uint4(hx, hz, hx, hz);
    *(uint4*)(rb + 512) = make_uint4(lx, lz, 0u, 0u);
}

// kpart layout: float kpart[NCHUNK][nG + nP]; slot = blockIdx.y.
__global__ void __launch_bounds__(BLOCK, 2)
nn_kernel(const uint4* __restrict__ recQ, const uint4* __restrict__ recB,
          float* __restrict__ kpart, int N, int M, int B) {
    const int z = blockIdx.z;
    const bool dirX = (z < B);
    const int b = dirX ? z : z - B;
    const int NQ = dirX ? N : M;
    const int NR = dirX ? M : N;
    const uint4* Qr = recQ + (dirX ? 0 : (size_t)B * N) + (size_t)b * NQ;
    const int chunk = NR / NCHUNK;                  // 4096 refs = 128 tiles
    // recB in uint4 units: 2 uint4 per point.
    const uint4* Rb4 = recB + (dirX ? (size_t)B * N * 2 : 0)
                       + ((size_t)b * NR + (size_t)blockIdx.y * chunk) * 2;
    const int nGP = B * (N + M);
    float* outK = kpart + (size_t)blockIdx.y * nGP + (dirX ? 0 : B * N) + (size_t)b * NQ;

    const int tid = threadIdx.x;
    const int lane = tid & 63;
    const int wave = tid >> 6;
    const int m = lane & 31;
    const unsigned int loMask = (lane >= 32) ? 0u : 0xFFFFFFFFu;
    const int qBase = (blockIdx.x * WAVES + wave) * QPW;

    // ---- A fragments (two 32-row groups)
    const uint4 q0 = Qr[qBase + m];
    const uint4 q1 = Qr[qBase + 32 + m];
    union { uint4 v; short8 s; } a;
    a.v.x = q0.x;                                   // (qxh, qyh)
    a.v.y = (q0.y & 0xFFFFu) | 0x3F800000u;         // (qzh, 1.0bf16)
    a.v.z = q0.z & loMask;                          // (qxl, qyl) | 0
    a.v.w = q0.w & 0xFFFFu & loMask;                // (qzl, 0)   | 0
    const short8 A0 = a.s;
    a.v.x = q1.x;
    a.v.y = (q1.y & 0xFFFFu) | 0x3F800000u;
    a.v.z = q1.z & loMask;
    a.v.w = q1.w & 0xFFFFu & loMask;
    const short8 A1 = a.s;

    f32x16 k0, k1, zc;
    #pragma unroll
    for (int r = 0; r < 16; ++r) { k0[r] = -INFINITY; k1[r] = -INFINITY; zc[r] = 0.0f; }

    // Quarter-chunk rotation (32 tiles) per wave/block: de-convoys L2 reads;
    // fold is order-independent; all addresses wrap via &127 (in-bounds).
    const int rot = ((wave + blockIdx.x) & 3) << 5;

    // One group = 8 tiles = 4 iterations. Lane l reads its pre-expanded 16B
    // fragment of tile t at Rb4[t*64 + lane]. Ping-pong S/T register groups
    // (8 uint4 each) = 4-iteration prefetch distance, all static names.
#define LOADG(P, g) do {                                                     \
        const uint4* p_ = Rb4 + (size_t)((((g) * 8 + rot) & 127) * 64) + lane; \
        P##0 = p_[0];   P##1 = p_[64];  P##2 = p_[128]; P##3 = p_[192];      \
        P##4 = p_[256]; P##5 = p_[320]; P##6 = p_[384]; P##7 = p_[448];      \
    } while (0)

#define DO2(ba, bb) do {                                                     \
        U4S ua_, ub_; ua_.v = (ba); ub_.v = (bb);                            \
        const f32x16 c0_ = MFMA(A0, ua_.s, zc);                              \
        const f32x16 c1_ = MFMA(A0, ub_.s, zc);                              \
        const f32x16 c2_ = MFMA(A1, ua_.s, zc);                              \
        const f32x16 c3_ = MFMA(A1, ub_.s, zc);                              \
        _Pragma("unroll")                                                    \
        for (int r = 0; r < 16; ++r)                                         \
            k0[r] = fmaxf(fmaxf(c0_[r], c1_[r]), k0[r]);                     \
        _Pragma("unroll")                                                    \
        for (int r = 0; r < 16; ++r)                                         \
            k1[r] = fmaxf(fmaxf(c2_[r], c3_[r]), k1[r]);                     \
    } while (0)

#define COMPG(P) do {                                                        \
        DO2(P##0, P##1); DO2(P##2, P##3);                                    \
        DO2(P##4, P##5); DO2(P##6, P##7);                                    \
    } while (0)

    uint4 S0, S1, S2, S3, S4, S5, S6, S7;
    uint4 T0, T1, T2, T3, T4, T5, T6, T7;
    LOADG(S, 0);
    #pragma unroll 1
    for (int g = 0; g < 16; g += 2) {
        LOADG(T, g + 1);       // prefetch next group (4 iters ahead)
        COMPG(S);
        LOADG(S, g + 2);       // g=14 -> group 16 wraps to rot: valid, unused
        COMPG(T);
    }
#undef LOADG
#undef DO2
#undef COMPG

    // ---- epilogue: LDS transpose, then each lane max-reduces one query row.
    // C/D layout: col=lane&31, row=(r&3)+8*(r>>2)+4*(lane>>5).
    // Wave-private region -> no barrier needed anywhere.
    __shared__ float sT[WAVES][64][36];             // +4 pad: conflict-free
    #pragma unroll
    for (int r = 0; r < 16; ++r) {
        const int row = (r & 3) + 8 * (r >> 2) + 4 * (lane >> 5);
        sT[wave][row][m]      = k0[r];              // group 0 -> rows 0..31
        sT[wave][32 + row][m] = k1[r];              // group 1 -> rows 32..63
    }
    // compiler inserts the lgkmcnt waits.
    const float4* rowp = (const float4*)&sT[wave][lane][0];
    float4 m01 = rowp[0];
    #pragma unroll
    for (int kk = 1; kk < 8; ++kk) {
        const float4 t = rowp[kk];
        m01.x = fmaxf(m01.x, t.x); m01.y = fmaxf(m01.y, t.y);
        m01.z = fmaxf(m01.z, t.z); m01.w = fmaxf(m01.w, t.w);
    }
    const float cmax = fmaxf(fmaxf(m01.x, m01.y), fmaxf(m01.z, m01.w));
    outK[qBase + lane] = cmax;                      // coalesced, no atomics
}

// d2 = max(0, ||q||^2 - 2*max(kpart[0], kpart[1])); weighted means, one
// atomicAdd per block. q2 precomputed fp32 in prep.
__global__ void __launch_bounds__(BLOCK)
reduce_kernel(const float* __restrict__ kpart, const float* __restrict__ q2,
              int nG, int nP, float invx, float invy, float* __restrict__ out) {
    const int total = nG + nP;
    float local = 0.0f;
    for (int idx = blockIdx.x * blockDim.x + threadIdx.x; idx < total;
         idx += gridDim.x * blockDim.x) {
        const float c = fmaxf(kpart[idx], kpart[total + idx]);
        const float inv = (idx < nG) ? invx : invy;
        local += fmaxf(q2[idx] - 2.0f * c, 0.0f) * inv;
    }
    __shared__ float waveSums[BLOCK / 64];
    float v = local;
    #pragma unroll
    for (int off = 32; off; off >>= 1) v += __shfl_xor(v, off);
    if ((threadIdx.x & 63) == 0) waveSums[threadIdx.x >> 6] = v;
    __syncthreads();
    if (threadIdx.x == 0) {
        float s = 0.0f;
        #pragma unroll
        for (int w = 0; w < BLOCK / 64; ++w) s += waveSums[w];
        atomicAdd(out, s);
    }
}

extern "C" void kernel_launch(void* const* d_in, const int* in_sizes, int n_in,
                              void* d_out, int out_size, void* d_ws, size_t ws_size,
                              hipStream_t stream) {
    const float* gts   = (const float*)d_in[0];   // [B, N, 3]
    const float* preds = (const float*)d_in[1];   // [B, M, 3]
    float* out = (float*)d_out;

    const int B = 8;
    const int N = in_sizes[0] / (B * 3);
    const int M = in_sizes[1] / (B * 3);
    const int nG = B * N, nP = B * M;

    uint4* recQ = (uint4*)d_ws;                                // (nG+nP)*16B (2 MB)
    unsigned char* recB = (unsigned char*)(recQ + nG + nP);    // (nG+nP)*32B (4 MB)
    float* kpart = (float*)(recB + (size_t)(nG + nP) * 32);    // NCHUNK*(nG+nP) (1 MB)
    float* q2    = kpart + (size_t)NCHUNK * (nG + nP);         // (nG+nP) (0.5 MB)

    prep_kernel<<<(nG + nP + BLOCK - 1) / BLOCK, BLOCK, 0, stream>>>(
        gts, preds, nG, nP, recQ, recB, q2, out);

    dim3 grid(N / (WAVES * QPW), NCHUNK, 2 * B);  // 32 x 2 x 16 = 1024 blocks
    nn_kernel<<<grid, BLOCK, 0, stream>>>(recQ, (const uint4*)recB, kpart, N, M, B);

    reduce_kernel<<<256, BLOCK, 0, stream>>>(
        kpart, q2, nG, nP, 1.0f / (float)nG, 1.0f / (float)nP, out);
}